// Round 13
// baseline (59.684 us; speedup 1.0000x reference)
//
#include <hip/hip_runtime.h>
#include <math.h>

// Problem constants: V=50000, D=100, B=16, S=128, U=100, L=2
#define NB 16
#define SS 128
#define DD 100
#define KK 100
#define T_TILE 8            // output positions per block
#define P_HALO 11           // T_TILE + 3 (dependency cone)
#define NTILES 16           // SS / T_TILE
#define NT 768              // 12 waves = 4 d-quarters (h) x 3 pos-groups (g)
#define NWAVES 12

__device__ __forceinline__ float dot4(const float4 a, const float4 b) {
  return a.x * b.x + a.y * b.y + a.z * b.z + a.w * b.w;
}

// ---------------------------------------------------------------------------
// One projection stage, d-split decomposition.
//   Staging: R12's proven chunked double-buffered transpose (5 x 16KB chunks,
//   1-chunk prefetch distance, layout [part][r][k] -> conflict-free).
//   FMA: wave (h,g): d4 == h (mod 4), positions 4g+e (e<4); lane owns k-pair
//   (lane, lane+50). V read once per (d4, k-pair), FMA'd across 4 positions.
//   Partials: two-round reduction into [2][12][50] overlay on vt, then h==0
//   waves combine (CM folds the epilogue):
//     CM 1: m[p][k] = |Y|^2 * iv                      (stage 1)
//     CM 2: m[p][k] = |w0 Y(p)+w1 Y(p+1)|^2 * iv      (stage 2 + window)
//     CM 3: y2[p][k] = Y raw; publishes invvn          (stage 3)
// ---------------------------------------------------------------------------
template<int MODE, int CM, int PMAXF, int PMAXC>
__device__ __forceinline__ void run_stage(
    const float* __restrict__ gvr, const float* __restrict__ gvi,
    float4 (*__restrict__ vt)[1000],
    const float4 (*__restrict__ bxr)[25], const float4 (*__restrict__ bxi)[25],
    float* __restrict__ mflat, float2* __restrict__ y2flat,
    float* __restrict__ invvn,
    const float* __restrict__ es, const float* __restrict__ sc,
    const int tid, const int lane, const int h, const int g,
    const bool act, const int t0)
{
  // --- staging address pattern (identical to R12) ---
  const int e0 = tid;                 // always < 1000
  const int e1 = tid + NT;            // valid for tid < 232
  const int p0 = e0 / 500, rm0 = e0 % 500, r0_ = rm0 / 100, k0_ = rm0 % 100;
  const int p1 = e1 / 500, rm1 = e1 % 500, r1_ = rm1 / 100, k1_ = rm1 % 100;
  const float* g0 = (p0 ? gvi : gvr) + k0_ * DD + 4 * r0_;
  const float* g1 = (p1 ? gvi : gvr) + k1_ * DD + 4 * r1_;

  float4 pv0, pv1;
  pv0 = *(const float4*)(g0);                      // chunk 0
  if (e1 < 1000) pv1 = *(const float4*)(g1);
  vt[0][e0] = pv0;
  if (e1 < 1000) vt[0][e1] = pv1;
  __syncthreads();

  float ar[4][2] = {{0.f,0.f},{0.f,0.f},{0.f,0.f},{0.f,0.f}};
  float ai[4][2] = {{0.f,0.f},{0.f,0.f},{0.f,0.f},{0.f,0.f}};
  float n0 = 0.f, n1 = 0.f;
  const int k0 = lane;                // act => lane < 50; owns (k0, k0+50)

  for (int c = 0; c < 5; ++c) {
    const int buf = c & 1;
    if (c + 1 < 5) {                                 // prefetch 1 chunk ahead
      pv0 = *(const float4*)(g0 + 20 * (c + 1));
      if (e1 < 1000) pv1 = *(const float4*)(g1 + 20 * (c + 1));
    }
    if (act) {
      const float4* vb = vt[buf];
#pragma unroll
      for (int r = 0; r < 5; ++r) {
        const int d4 = 5 * c + r;
        if ((d4 & 3) == h) {          // this wave's d4 subset (wave-uniform)
          const float4 Vr0 = vb[r * 100 + k0];
          const float4 Vr1 = vb[r * 100 + 50 + k0];
          const float4 Vi0 = vb[500 + r * 100 + k0];
          const float4 Vi1 = vb[500 + r * 100 + 50 + k0];
          n0 += dot4(Vr0, Vr0) + dot4(Vi0, Vi0);
          n1 += dot4(Vr1, Vr1) + dot4(Vi1, Vi1);
#pragma unroll
          for (int e = 0; e < 4; ++e) {
            const int p = 4 * g + e;
            if (p <= PMAXF) {
              const float4 xr = bxr[p][d4];
              if (MODE == 0) {
                const float4 xi = bxi[p][d4];
                ar[e][0] += dot4(Vr0, xr) + dot4(Vi0, xi);
                ai[e][0] += dot4(Vr0, xi) - dot4(Vi0, xr);
                ar[e][1] += dot4(Vr1, xr) + dot4(Vi1, xi);
                ai[e][1] += dot4(Vr1, xi) - dot4(Vi1, xr);
              } else {
                ar[e][0] += dot4(Vr0, xr);
                ai[e][0] += dot4(Vi0, xr);
                ar[e][1] += dot4(Vr1, xr);
                ai[e][1] += dot4(Vi1, xr);
              }
            }
          }
        }
      }
    }
    if (c + 1 < 5) {                                 // write-late, other buffer
      const int nb = buf ^ 1;
      vt[nb][e0] = pv0;
      if (e1 < 1000) vt[nb][e1] = pv1;
    }
    __syncthreads();
  }

  // --- two-round partial reduction (overlay on dead vt) ---
  float4* partlp = &vt[0][0];                    // [2][12][50] = 1200 f4
  float2* nrmp   = (float2*)(&vt[0][0] + 1200);  // [2][50]
  if (h < 2 && act) {
#pragma unroll
    for (int e = 0; e < 4; ++e) {
      const int p = 4 * g + e;
      if (p <= PMAXF)
        partlp[h * 600 + p * 50 + lane] =
            make_float4(ar[e][0], ai[e][0], ar[e][1], ai[e][1]);
    }
    if (g == 0) nrmp[h * 50 + lane] = make_float2(n0, n1);
  }
  __syncthreads();
  if (h >= 2 && act) {
    const int j = h - 2;
#pragma unroll
    for (int e = 0; e < 4; ++e) {
      const int p = 4 * g + e;
      if (p <= PMAXF) {
        float4 s = partlp[j * 600 + p * 50 + lane];
        s.x += ar[e][0]; s.y += ai[e][0]; s.z += ar[e][1]; s.w += ai[e][1];
        partlp[j * 600 + p * 50 + lane] = s;
      }
    }
    if (g == 0) {
      float2 q = nrmp[j * 50 + lane];
      q.x += n0; q.y += n1;
      nrmp[j * 50 + lane] = q;
    }
  }
  __syncthreads();

  // --- combine (h==0 waves; g splits positions) ---
  if (h == 0 && act) {
    const float2 qa = nrmp[lane], qb = nrmp[50 + lane];
    const float iv0 = 1.f / (qa.x + qb.x);
    const float iv1 = 1.f / (qa.y + qb.y);
#pragma unroll
    for (int e = 0; e < 4; ++e) {
      const int p = 4 * g + e;
      if (p <= PMAXC) {
        float4 s = partlp[p * 50 + lane];
        {
          const float4 s2 = partlp[600 + p * 50 + lane];
          s.x += s2.x; s.y += s2.y; s.z += s2.z; s.w += s2.w;
        }
        if (CM == 1) {
          mflat[p * KK + lane]      = (s.x * s.x + s.y * s.y) * iv0;
          mflat[p * KK + 50 + lane] = (s.z * s.z + s.w * s.w) * iv1;
        } else if (CM == 2) {
          float4 u = partlp[(p + 1) * 50 + lane];
          {
            const float4 u2 = partlp[600 + (p + 1) * 50 + lane];
            u.x += u2.x; u.y += u2.y; u.z += u2.z; u.w += u2.w;
          }
          const int t = t0 + p;
          const float w0 = ((t     < SS) ? es[t]     : 1.f) / sc[0];
          const float w1 = ((t + 1 < SS) ? es[t + 1] : 1.f) / sc[1];
          const float r0 = w0 * s.x + w1 * u.x, i0 = w0 * s.y + w1 * u.y;
          const float r1 = w0 * s.z + w1 * u.z, i1 = w0 * s.w + w1 * u.w;
          mflat[p * KK + lane]      = (r0 * r0 + i0 * i0) * iv0;
          mflat[p * KK + 50 + lane] = (r1 * r1 + i1 * i1) * iv1;
        } else {
          y2flat[p * KK + lane]      = make_float2(s.x, s.y);
          y2flat[p * KK + 50 + lane] = make_float2(s.z, s.w);
        }
      }
    }
    if (CM == 3 && g == 0) { invvn[lane] = iv0; invvn[50 + lane] = iv1; }
  }
  __syncthreads();
}

// ---------------------------------------------------------------------------
// Fused kernel: block = (batch, tile of 8 positions). Full 3-stage pipeline
// for its 11-position halo cone; writes partial probs.
// ---------------------------------------------------------------------------
__global__ __launch_bounds__(NT) void k_fused(
    const int* __restrict__ seq,
    const float* __restrict__ ampT, const float* __restrict__ phT,
    const float* __restrict__ pkr, const float* __restrict__ pki,
    const float* __restrict__ mkr, const float* __restrict__ mki,
    float* __restrict__ part)
{
  __shared__ float4 vt[2][1000];        // 32000 B: V dbuf / partials overlay
  __shared__ float4 xr4[P_HALO][25];    // stage-1 phi real
  __shared__ float4 xi4[P_HALO][25];    // stage-1 phi imag
  __shared__ float4 m4[P_HALO][25];     // m1 then m2
  __shared__ float2 y2[P_HALO][KK];     // stage-3 Y
  __shared__ float es[SS];
  __shared__ float wnl[SS];
  __shared__ float invvn[KK];
  __shared__ float redw[NWAVES];
  __shared__ float sc[3];               // E, Z1, Z2

  const int tid  = threadIdx.x;
  const int lane = tid & 63;
  const int wid  = tid >> 6;
  const int h    = wid & 3;             // d-quarter (d4 mod 4)
  const int g    = wid >> 2;            // position group (0..2)
  const bool act = lane < 50;
  const int bt   = blockIdx.x;
  const int b    = bt >> 4;
  const int tile = bt & 15;
  const int t0   = tile * T_TILE;
  const int sb   = b * SS;

  // --- prologue A: norms + exp for ALL 128 positions of this batch ---
  if (tid < 4 * SS) {                   // waves 0..7 exactly
    const int t = tid >> 2, q = tid & 3;
    const int row = seq[sb + t];
    const float* ap = ampT + (long)row * DD + q;
    float s = 0.f;
#pragma unroll
    for (int i = 0; i < 25; ++i) { const float a = ap[4*i]; s += a * a; }
    s += __shfl_xor(s, 1, 64);
    s += __shfl_xor(s, 2, 64);
    if (q == 0) { const float nrm = sqrtf(s); wnl[t] = nrm; es[t] = expf(nrm); }
  }
  __syncthreads();

  // --- E and closed-form softmax denominators ---
  {
    float v = (tid < SS) ? es[tid] : 0.f;
    for (int m = 32; m; m >>= 1) v += __shfl_xor(v, m, 64);
    if (lane == 0) redw[wid] = v;
  }
  // --- prologue B: phi = (amp/||amp||) * e^{i phase}; ZERO past seq end ---
  for (int idx = tid; idx < P_HALO * 25; idx += NT) {
    const int p = idx / 25, d4 = idx % 25;
    const int tp = t0 + p;
    float4 o_r = {0.f, 0.f, 0.f, 0.f}, o_i = {0.f, 0.f, 0.f, 0.f};
    if (tp < SS) {
      const int row = seq[sb + tp];
      const float4 a4 = *(const float4*)(ampT + (long)row * DD + 4 * d4);
      const float4 p4 = *(const float4*)(phT  + (long)row * DD + 4 * d4);
      const float inv = 1.0f / wnl[tp];
      float sv, cv;
      sincosf(p4.x, &sv, &cv); o_r.x = a4.x * inv * cv; o_i.x = a4.x * inv * sv;
      sincosf(p4.y, &sv, &cv); o_r.y = a4.y * inv * cv; o_i.y = a4.y * inv * sv;
      sincosf(p4.z, &sv, &cv); o_r.z = a4.z * inv * cv; o_i.z = a4.z * inv * sv;
      sincosf(p4.w, &sv, &cv); o_r.w = a4.w * inv * cv; o_i.w = a4.w * inv * sv;
    }
    xr4[p][d4] = o_r;
    xi4[p][d4] = o_i;
  }
  __syncthreads();
  if (tid == 0) {
    float E = 0.f;
    for (int w = 0; w < NWAVES; ++w) E += redw[w];
    sc[0] = E;
    sc[1] = E - es[0] + 1.0f;
    sc[2] = E - es[0] - es[1] + 2.0f;
  }
  __syncthreads();

  // --- stage 1: m1[p][k] = |<v0_k, phi_p>|^2 / ||v0_k||^2, p <= 10 ---
  run_stage<0, 1, 10, 10>(pkr, pki, vt, xr4, xi4, (float*)m4, nullptr, invvn,
                          es, sc, tid, lane, h, g, act, t0);
  // --- stage 2: m2 = |2-tap window of <v1, m1>|^2 * iv, p <= 9 (folded) ---
  run_stage<1, 2, 10, 9>(pkr + DD * DD, pki + DD * DD, vt, m4, m4,
                         (float*)m4, nullptr, invvn, es, sc,
                         tid, lane, h, g, act, t0);
  // --- stage 3: y2[p][k] = <u_k, m2_p> raw, p <= 9; publishes invvn ---
  run_stage<1, 3, 9, 9>(mkr, mki, vt, m4, m4, nullptr, (float2*)y2, invvn,
                        es, sc, tid, lane, h, g, act, t0);

  // --- final: 3-tap window, square, * wn[t] * invvn_U[k]; sum over own p ---
  {
    const float E = sc[0], Z1 = sc[1], Z2 = sc[2];
    for (int idx = tid; idx < T_TILE * KK; idx += NT) {
      const int p = idx / KK, k = idx - p * KK;
      const int t = t0 + p;                         // < 128 always
      const float w0 = es[t] / E;
      const float w1 = ((t + 1 < SS) ? es[t + 1] : 1.f) / Z1;
      const float w2 = ((t + 2 < SS) ? es[t + 2] : 1.f) / Z2;
      const float2 ya = y2[p][k], yb = y2[p + 1][k], yc = y2[p + 2][k];
      const float qr = w0 * ya.x + w1 * yb.x + w2 * yc.x;
      const float qi = w0 * ya.y + w1 * yb.y + w2 * yc.y;
      ((float*)m4)[p * KK + k] = wnl[t] * (qr * qr + qi * qi) * invvn[k];
    }
  }
  __syncthreads();
  if (tid < KK) {
    float s = 0.f;
#pragma unroll
    for (int p = 0; p < T_TILE; ++p) s += ((float*)m4)[p * KK + tid];
    part[bt * KK + tid] = s;
  }
}

// ---------------------------------------------------------------------------
// Output: probs[b,k] = sum_tiles part; out = probs @ dense_w + dense_b
// ---------------------------------------------------------------------------
__global__ __launch_bounds__(128) void k_out(
    const float* __restrict__ part, const float* __restrict__ dw,
    const float* __restrict__ db, float* __restrict__ out)
{
  __shared__ float pr[KK];
  const int b = blockIdx.x, tid = threadIdx.x;
  if (tid < KK) {
    float s = 0.f;
#pragma unroll
    for (int q = 0; q < NTILES; ++q) s += part[(b * NTILES + q) * KK + tid];
    pr[tid] = s;
  }
  __syncthreads();
  if (tid < 2) {
    float s = db[tid];
    for (int k = 0; k < KK; ++k) s += pr[k] * dw[k * 2 + tid];
    out[b * 2 + tid] = s;
  }
}

// ---------------------------------------------------------------------------
extern "C" void kernel_launch(void* const* d_in, const int* in_sizes, int n_in,
                              void* d_out, int out_size, void* d_ws, size_t ws_size,
                              hipStream_t stream) {
  const int*   seq  = (const int*)d_in[0];
  const float* ampT = (const float*)d_in[1];
  const float* phT  = (const float*)d_in[2];
  const float* pkr  = (const float*)d_in[3];
  const float* pki  = (const float*)d_in[4];
  const float* mkr  = (const float*)d_in[5];
  const float* mki  = (const float*)d_in[6];
  const float* dw   = (const float*)d_in[7];
  const float* db   = (const float*)d_in[8];
  float* out  = (float*)d_out;
  float* part = (float*)d_ws;                 // 256*100 floats = 102.4 KB

  k_fused<<<NB * NTILES, NT, 0, stream>>>(seq, ampT, phT, pkr, pki, mkr, mki, part);
  k_out  <<<NB,          128, 0, stream>>>(part, dw, db, out);
}

// Round 14
// 34.196 us; speedup vs baseline: 1.7454x; 1.7454x over previous
//
#include <hip/hip_runtime.h>
#include <math.h>

// Problem constants: V=50000, D=100, B=16, S=128, U=100, L=2
#define NB 16
#define SS 128
#define DD 100
#define KK 100
#define T_TILE 8            // output positions per block
#define P_HALO 11           // T_TILE + 3 (dependency cone)
#define NTILES 16           // SS / T_TILE
#define NT 768              // threads per block (12 waves, 3/SIMD)
#define NWAVES 12
#define CH_D4 5             // d4-rows per chunk
#define NCHUNK 5            // 25 d4-rows total (D=100)

__device__ __forceinline__ float dot4(const float4 a, const float4 b) {
  return a.x * b.x + a.y * b.y + a.z * b.z + a.w * b.w;
}

// ---------------------------------------------------------------------------
// Chunk staging (R12-proven addresses). Thread tid covers granules e0=tid and
// e1=tid+NT (<1000). element e: part=e/500, r=(e%500)/100, k=e%100;
// source = gv_part + k*DD + 4*(c*CH_D4 + r).
// ---------------------------------------------------------------------------
__device__ __forceinline__ void ld_chunk(const float* __restrict__ gvr,
                                         const float* __restrict__ gvi,
                                         int c, int tid,
                                         float4& pv0, float4& pv1) {
  const int e0 = tid;
  const int p0 = e0 / 500, rm0 = e0 % 500, r0_ = rm0 / 100, k0_ = rm0 % 100;
  pv0 = *(const float4*)((p0 ? gvi : gvr) + k0_ * DD + 4 * (CH_D4 * c + r0_));
  const int e1 = tid + NT;
  if (e1 < 1000) {
    const int p1 = e1 / 500, rm1 = e1 % 500, r1_ = rm1 / 100, k1_ = rm1 % 100;
    pv1 = *(const float4*)((p1 ? gvi : gvr) + k1_ * DD + 4 * (CH_D4 * c + r1_));
  }
}
__device__ __forceinline__ void st_chunk(float4 (*__restrict__ vt)[1000],
                                         int buf, int tid,
                                         const float4& pv0, const float4& pv1) {
  vt[buf][tid] = pv0;
  if (tid + NT < 1000) vt[buf][tid + NT] = pv1;
}

// ---------------------------------------------------------------------------
// Per-chunk accumulate for BOTH of a wave's slots (same k -> V fragments read
// once) + in-loop row norm (register-fed, replaces any global norm pass).
// MODE 0: complex x (stage 1).  MODE 1: real x (stages 2, 3).
// ---------------------------------------------------------------------------
template<int MODE>
__device__ __forceinline__ void accum_pair(
    const float4* __restrict__ vtb,
    const float4 (*__restrict__ bxr)[25], const float4 (*__restrict__ bxi)[25],
    int p0, int p1, bool a0, bool a1, int k, int c,
    float& r0a, float& i0a, float& r1a, float& i1a, float& n0)
{
#pragma unroll
  for (int r = 0; r < CH_D4; ++r) {
    const int d4 = c * CH_D4 + r;
    const float4 vr4 = vtb[r * KK + k];          // read once,
    const float4 vi4 = vtb[500 + r * KK + k];    // used by both slots + norm
    n0 += dot4(vr4, vr4) + dot4(vi4, vi4);
    if (a0) {
      const float4 x4 = bxr[p0][d4];
      if (MODE == 0) {
        const float4 z4 = bxi[p0][d4];
        r0a += dot4(vr4, x4) + dot4(vi4, z4);
        i0a += dot4(vr4, z4) - dot4(vi4, x4);
      } else {
        r0a += dot4(vr4, x4);
        i0a += dot4(vi4, x4);
      }
    }
    if (a1) {
      const float4 x4 = bxr[p1][d4];
      if (MODE == 0) {
        const float4 z4 = bxi[p1][d4];
        r1a += dot4(vr4, x4) + dot4(vi4, z4);
        i1a += dot4(vr4, z4) - dot4(vi4, x4);
      } else {
        r1a += dot4(vr4, x4);
        i1a += dot4(vi4, x4);
      }
    }
  }
}

// ---------------------------------------------------------------------------
// One projection stage. On entry pv0/pv1 hold THIS stage's chunk 0 (issued a
// full stage earlier); on exit they hold gnr's chunk 0 (issued during the
// last chunk's FMA window -> stage-boundary VMEM latency hidden).
// MODE 0: writes m[p][k] = |Y|^2/n0 (n0 local).
// MODE 1: writes y2 = (ar,ai) raw; publishes invvn[kk]=1/n0 (waves 0..1
//         jointly cover all 100 k). Caller must __syncthreads() after return.
// ---------------------------------------------------------------------------
template<int MODE>
__device__ __forceinline__ void run_stage(
    const float* __restrict__ gvr, const float* __restrict__ gvi,
    const float* __restrict__ gnr, const float* __restrict__ gni,
    float4 (*__restrict__ vt)[1000],
    const float4 (*__restrict__ bxr)[25], const float4 (*__restrict__ bxi)[25],
    float* __restrict__ mflat, float2* __restrict__ y2flat,
    float* __restrict__ invvn, const int nslots,
    const int tid, const int lane, const int wid,
    float4& pv0, float4& pv1)
{
  st_chunk(vt, 0, tid, pv0, pv1);       // chunk 0 (preloaded long ago)
  __syncthreads();

  const int s0 = wid, s1 = wid + NWAVES;
  float a0r = 0.f, a0i = 0.f, a1r = 0.f, a1i = 0.f, n0 = 0.f;
  const int kk = (s0 & 1) * 50 + lane;     // s0,s1 share parity -> same k
  const int pp0 = s0 >> 1, pp1 = s1 >> 1;
  const bool act0 = (s0 < nslots), act1 = (s1 < nslots);

  for (int c = 0; c < NCHUNK; ++c) {
    const int buf = c & 1;
    if (c + 1 < NCHUNK)  ld_chunk(gvr, gvi, c + 1, tid, pv0, pv1);  // 1 ahead
    else if (gnr)        ld_chunk(gnr, gni, 0,     tid, pv0, pv1);  // x-stage
    if (lane < 50)
      accum_pair<MODE>(vt[buf], bxr, bxi, pp0, pp1, act0, act1, kk, c,
                       a0r, a0i, a1r, a1i, n0);
    if (c + 1 < NCHUNK)
      st_chunk(vt, buf ^ 1, tid, pv0, pv1);     // write-late, other buffer
    __syncthreads();
  }

  if (lane < 50) {
    const float rcp = 1.0f / n0;
    if (act0) {
      if (MODE == 0) mflat[pp0 * KK + kk] = (a0r * a0r + a0i * a0i) * rcp;
      else           y2flat[pp0 * KK + kk] = make_float2(a0r, a0i);
    }
    if (act1) {
      if (MODE == 0) mflat[pp1 * KK + kk] = (a1r * a1r + a1i * a1i) * rcp;
      else           y2flat[pp1 * KK + kk] = make_float2(a1r, a1i);
    }
    if (wid < 2) invvn[kk] = rcp;   // waves 0,1 cover k=0..49 / 50..99
  }
}

// ---------------------------------------------------------------------------
// Fused kernel: block = (batch, tile of 8 positions). Computes the full
// 3-stage pipeline for its halo cone (11 positions) and writes partial probs.
// ---------------------------------------------------------------------------
__global__ __launch_bounds__(NT) void k_fused(
    const int* __restrict__ seq,
    const float* __restrict__ ampT, const float* __restrict__ phT,
    const float* __restrict__ pkr, const float* __restrict__ pki,
    const float* __restrict__ mkr, const float* __restrict__ mki,
    float* __restrict__ part)
{
  __shared__ float4 vt[2][1000];        // 32000 B: V chunk double-buffer
  __shared__ float4 xr4[P_HALO][25];    // stage-1 phi real
  __shared__ float4 xi4[P_HALO][25];    // stage-1 phi imag
  __shared__ float4 m4[P_HALO][25];     // m vector (m1, then m2, then scratch)
  __shared__ float2 y2[P_HALO][KK];     // projection pair outputs
  __shared__ float es[SS];
  __shared__ float wnl[SS];
  __shared__ float invvn[KK];
  __shared__ float redw[NWAVES];
  __shared__ float sc[3];               // E, Z1, Z2

  const int tid  = threadIdx.x;
  const int lane = tid & 63;
  const int wid  = tid >> 6;
  const int bt   = blockIdx.x;
  const int b    = bt >> 4;
  const int tile = bt & 15;
  const int t0   = tile * T_TILE;
  const int sb   = b * SS;

  // stage-1 chunk 0: issued FIRST, hidden under the whole prologue
  float4 pv0, pv1;
  ld_chunk(pkr, pki, 0, tid, pv0, pv1);

  // --- prologue A: norms + exp for ALL 128 positions of this batch ---
  if (tid < 4 * SS) {                   // waves 0..7 exactly
    const int t = tid >> 2, q = tid & 3;
    const int row = seq[sb + t];
    const float* ap = ampT + (long)row * DD + q;
    float s = 0.f;
#pragma unroll
    for (int i = 0; i < 25; ++i) { const float a = ap[4*i]; s += a * a; }
    s += __shfl_xor(s, 1, 64);
    s += __shfl_xor(s, 2, 64);
    if (q == 0) { const float nrm = sqrtf(s); wnl[t] = nrm; es[t] = expf(nrm); }
  }
  __syncthreads();

  // --- E and closed-form softmax denominators ---
  {
    float v = (tid < SS) ? es[tid] : 0.f;
    for (int m = 32; m; m >>= 1) v += __shfl_xor(v, m, 64);
    if (lane == 0) redw[wid] = v;
  }
  // --- prologue B: phi = (amp/||amp||) * e^{i phase} for halo positions ---
  for (int idx = tid; idx < P_HALO * 25; idx += NT) {
    const int p = idx / 25, d4 = idx % 25;
    const int tp = t0 + p;
    float4 o_r = {0.f, 0.f, 0.f, 0.f}, o_i = {0.f, 0.f, 0.f, 0.f};
    if (tp < SS) {
      const int row = seq[sb + tp];
      const float4 a4 = *(const float4*)(ampT + (long)row * DD + 4 * d4);
      const float4 p4 = *(const float4*)(phT  + (long)row * DD + 4 * d4);
      const float inv = 1.0f / wnl[tp];
      float sv, cv;
      sincosf(p4.x, &sv, &cv); o_r.x = a4.x * inv * cv; o_i.x = a4.x * inv * sv;
      sincosf(p4.y, &sv, &cv); o_r.y = a4.y * inv * cv; o_i.y = a4.y * inv * sv;
      sincosf(p4.z, &sv, &cv); o_r.z = a4.z * inv * cv; o_i.z = a4.z * inv * sv;
      sincosf(p4.w, &sv, &cv); o_r.w = a4.w * inv * cv; o_i.w = a4.w * inv * sv;
    }
    xr4[p][d4] = o_r;
    xi4[p][d4] = o_i;
  }
  __syncthreads();
  if (tid == 0) {
    float E = 0.f;
    for (int w = 0; w < NWAVES; ++w) E += redw[w];
    sc[0] = E;
    sc[1] = E - es[0] + 1.0f;
    sc[2] = E - es[0] - es[1] + 2.0f;
  }
  __syncthreads();

  // --- stage 1: m1[p][k] = |<v0_k, phi_p>|^2 / ||v0_k||^2 ---
  run_stage<0>(pkr, pki, pkr + DD * DD, pki + DD * DD, vt, xr4, xi4,
               (float*)m4, nullptr, invvn, 2 * P_HALO,
               tid, lane, wid, pv0, pv1);
  __syncthreads();

  // --- stage 2: y2[p][k] = (sum vr*m1, sum vi*m1); publishes invvn (L1) ---
  run_stage<1>(pkr + DD * DD, pki + DD * DD, mkr, mki, vt, m4, m4,
               nullptr, (float2*)y2, invvn, 2 * P_HALO,
               tid, lane, wid, pv0, pv1);
  __syncthreads();

  // --- m2 = 2-tap window of y2, squared, scaled by invvn (layer-1 norms) ---
  {
    const float E = sc[0], Z1 = sc[1];
    for (int idx = tid; idx < 10 * KK; idx += NT) {
      const int p = idx / KK, k = idx - p * KK;
      const int t = t0 + p;
      const float w0 = ((t     < SS) ? es[t]     : 1.f) / E;
      const float w1 = ((t + 1 < SS) ? es[t + 1] : 1.f) / Z1;
      const float2 ya = y2[p][k], yb = y2[p + 1][k];
      const float ar = w0 * ya.x + w1 * yb.x;
      const float ai = w0 * ya.y + w1 * yb.y;
      ((float*)m4)[p * KK + k] = (ar * ar + ai * ai) * invvn[k];
    }
  }
  __syncthreads();

  // --- stage 3: y2[p][k] = (sum ur*m2, sum ui*m2), p < 10; publishes invvn ---
  run_stage<1>(mkr, mki, nullptr, nullptr, vt, m4, m4,
               nullptr, (float2*)y2, invvn, 20,
               tid, lane, wid, pv0, pv1);
  __syncthreads();

  // --- final: 3-tap window, square, * wn[t] * invvn_U[k]; sum over own p ---
  {
    const float E = sc[0], Z1 = sc[1], Z2 = sc[2];
    for (int idx = tid; idx < T_TILE * KK; idx += NT) {
      const int p = idx / KK, k = idx - p * KK;
      const int t = t0 + p;                         // < 128 always
      const float w0 = es[t] / E;
      const float w1 = ((t + 1 < SS) ? es[t + 1] : 1.f) / Z1;
      const float w2 = ((t + 2 < SS) ? es[t + 2] : 1.f) / Z2;
      const float2 ya = y2[p][k], yb = y2[p + 1][k], yc = y2[p + 2][k];
      const float qr = w0 * ya.x + w1 * yb.x + w2 * yc.x;
      const float qi = w0 * ya.y + w1 * yb.y + w2 * yc.y;
      ((float*)m4)[p * KK + k] = wnl[t] * (qr * qr + qi * qi) * invvn[k];
    }
  }
  __syncthreads();
  if (tid < KK) {
    float s = 0.f;
#pragma unroll
    for (int p = 0; p < T_TILE; ++p) s += ((float*)m4)[p * KK + tid];
    part[bt * KK + tid] = s;
  }
}

// ---------------------------------------------------------------------------
// Output: probs[b,k] = sum_tiles part; out = probs @ dense_w + dense_b
// ---------------------------------------------------------------------------
__global__ __launch_bounds__(128) void k_out(
    const float* __restrict__ part, const float* __restrict__ dw,
    const float* __restrict__ db, float* __restrict__ out)
{
  __shared__ float pr[KK];
  const int b = blockIdx.x, tid = threadIdx.x;
  if (tid < KK) {
    float s = 0.f;
#pragma unroll
    for (int q = 0; q < NTILES; ++q) s += part[(b * NTILES + q) * KK + tid];
    pr[tid] = s;
  }
  __syncthreads();
  if (tid < 2) {
    float s = db[tid];
    for (int k = 0; k < KK; ++k) s += pr[k] * dw[k * 2 + tid];
    out[b * 2 + tid] = s;
  }
}

// ---------------------------------------------------------------------------
extern "C" void kernel_launch(void* const* d_in, const int* in_sizes, int n_in,
                              void* d_out, int out_size, void* d_ws, size_t ws_size,
                              hipStream_t stream) {
  const int*   seq  = (const int*)d_in[0];
  const float* ampT = (const float*)d_in[1];
  const float* phT  = (const float*)d_in[2];
  const float* pkr  = (const float*)d_in[3];
  const float* pki  = (const float*)d_in[4];
  const float* mkr  = (const float*)d_in[5];
  const float* mki  = (const float*)d_in[6];
  const float* dw   = (const float*)d_in[7];
  const float* db   = (const float*)d_in[8];
  float* out  = (float*)d_out;
  float* part = (float*)d_ws;                 // 256*100 floats = 102.4 KB

  k_fused<<<NB * NTILES, NT, 0, stream>>>(seq, ampT, phT, pkr, pki, mkr, mki, part);
  k_out  <<<NB,          128, 0, stream>>>(part, dw, db, out);
}